// Round 2
// baseline (242.442 us; speedup 1.0000x reference)
//
#include <hip/hip_runtime.h>
#include <hip/hip_bf16.h>
#include <math.h>

#define B_ 16
#define C_ 67
#define H_ 128
#define W_ 128
#define MAIN_ 64
#define G_ 8
#define K2_ 9
#define PM_ 72
#define PR_ 9

// ---------------- Kernel 1: global average pool ----------------
// grid: B*C blocks, 256 threads. Each block reduces one (b,c) plane (16384 floats).
__global__ __launch_bounds__(256) void pool_kernel(const float* __restrict__ x,
                                                   float* __restrict__ pooled) {
    int bc = blockIdx.x;
    const float4* p4 = (const float4*)(x + (size_t)bc * (H_ * W_));
    int tid = threadIdx.x;
    float s = 0.f;
    const int n4 = H_ * W_ / 4;  // 4096
    for (int i = tid; i < n4; i += 256) {
        float4 v = p4[i];
        s += (v.x + v.y) + (v.z + v.w);
    }
    // wave64 reduce
    for (int off = 32; off > 0; off >>= 1) s += __shfl_down(s, off, 64);
    __shared__ float red[4];
    if ((tid & 63) == 0) red[tid >> 6] = s;
    __syncthreads();
    if (tid == 0) {
        float t = (red[0] + red[1]) + (red[2] + red[3]);
        pooled[bc] = t * (1.0f / (H_ * W_));
    }
}

// ---------------- Kernel 2: dynamic kernel generation ----------------
// grid: B blocks, 128 threads. Threads 0..71 handle main path, 96..104 handle rem path.
__global__ __launch_bounds__(128) void gen_kernel(
    const float* __restrict__ pooled,
    const float* __restrict__ w_main, const float* __restrict__ w_gate_main,
    const float* __restrict__ w_rem,  const float* __restrict__ w_gate_rem,
    const float* __restrict__ gm, const float* __restrict__ bm,
    const float* __restrict__ mm, const float* __restrict__ vm,
    const float* __restrict__ gr, const float* __restrict__ br,
    const float* __restrict__ mr, const float* __restrict__ vr,
    float* __restrict__ km_out, float* __restrict__ kr_out) {
    int b = blockIdx.x;
    int t = threadIdx.x;
    __shared__ float pl[C_];
    __shared__ float km0[PM_];
    __shared__ float kmb[PM_];
    __shared__ float kr0[PR_];
    __shared__ float krb[PR_];
    if (t < C_) pl[t] = pooled[b * C_ + t];
    __syncthreads();
    if (t < PM_) {
        float s = 0.f;
        for (int c = 0; c < C_; ++c) s += pl[c] * w_main[t * C_ + c];
        km0[t] = s;
    }
    if (t >= 96 && t < 96 + PR_) {
        int p = t - 96;
        float s = 0.f;
        for (int c = 0; c < C_; ++c) s += pl[c] * w_rem[p * C_ + c];
        kr0[p] = s;
    }
    __syncthreads();
    if (t < PM_) {
        float gsum = 0.f;
        for (int q = 0; q < PM_; ++q) gsum += km0[q] * w_gate_main[t * PM_ + q];
        float v = km0[t] * (1.f / (1.f + expf(-gsum)));
        v = gm[t] * (v - mm[t]) * rsqrtf(vm[t] + 1e-5f) + bm[t];
        kmb[t] = v;
    }
    if (t >= 96 && t < 96 + PR_) {
        int p = t - 96;
        float gsum = 0.f;
        for (int q = 0; q < PR_; ++q) gsum += kr0[q] * w_gate_rem[p * PR_ + q];
        float v = kr0[p] * (1.f / (1.f + expf(-gsum)));
        v = gr[p] * (v - mr[p]) * rsqrtf(vr[p] + 1e-5f) + br[p];
        krb[p] = v;
    }
    __syncthreads();
    if (t < PM_) {
        int base = (t / K2_) * K2_;
        float mx = -1e30f;
        for (int k = 0; k < K2_; ++k) mx = fmaxf(mx, kmb[base + k]);
        float den = 0.f;
        for (int k = 0; k < K2_; ++k) den += expf(kmb[base + k] - mx);
        km_out[b * PM_ + t] = expf(kmb[t] - mx) / den;
    }
    if (t >= 96 && t < 96 + PR_) {
        int p = t - 96;
        float mx = -1e30f;
        for (int k = 0; k < K2_; ++k) mx = fmaxf(mx, krb[k]);
        float den = 0.f;
        for (int k = 0; k < K2_; ++k) den += expf(krb[k] - mx);
        kr_out[b * PR_ + p] = expf(krb[p] - mx) / den;
    }
}

// ---------------- Kernel 3: dynamic 3x3 conv (reflect pad) + residual ----------------
// grid: (H/2, C, B), 256 threads = 2 rows x 128 cols of one (b,c) plane.
__global__ __launch_bounds__(256) void conv_kernel(const float* __restrict__ x,
                                                   const float* __restrict__ km,
                                                   const float* __restrict__ kr,
                                                   float* __restrict__ out) {
    int b = blockIdx.z;
    int c = blockIdx.y;
    int h = blockIdx.x * 2 + (threadIdx.x >> 7);
    int w = threadIdx.x & 127;

    const float* wp = (c < MAIN_) ? (km + ((size_t)b * G_ + (c >> 3)) * K2_)
                                  : (kr + (size_t)b * K2_);
    float k0 = wp[0], k1 = wp[1], k2 = wp[2],
          k3 = wp[3], k4 = wp[4], k5 = wp[5],
          k6 = wp[6], k7 = wp[7], k8 = wp[8];

    const float* xb = x + ((size_t)b * C_ + c) * (H_ * W_);
    int hm = (h == 0) ? 1 : h - 1;
    int hp = (h == H_ - 1) ? H_ - 2 : h + 1;
    int wm = (w == 0) ? 1 : w - 1;
    int wq = (w == W_ - 1) ? W_ - 2 : w + 1;

    const float* r0 = xb + hm * W_;
    const float* r1 = xb + h * W_;
    const float* r2 = xb + hp * W_;

    float c00 = r0[wm], c01 = r0[w], c02 = r0[wq];
    float c10 = r1[wm], c11 = r1[w], c12 = r1[wq];
    float c20 = r2[wm], c21 = r2[w], c22 = r2[wq];

    float o = k0 * c00 + k1 * c01 + k2 * c02
            + k3 * c10 + k4 * c11 + k5 * c12
            + k6 * c20 + k7 * c21 + k8 * c22;

    size_t idx = (((size_t)b * C_ + c) * H_ + h) * W_ + w;
    out[idx] = o;
    out[idx + (size_t)B_ * C_ * H_ * W_] = c11 - o;
}

extern "C" void kernel_launch(void* const* d_in, const int* in_sizes, int n_in,
                              void* d_out, int out_size, void* d_ws, size_t ws_size,
                              hipStream_t stream) {
    const float* x           = (const float*)d_in[0];
    const float* w_main      = (const float*)d_in[1];
    const float* w_gate_main = (const float*)d_in[2];
    const float* w_rem       = (const float*)d_in[3];
    const float* w_gate_rem  = (const float*)d_in[4];
    const float* gm = (const float*)d_in[5];
    const float* bm = (const float*)d_in[6];
    const float* mm = (const float*)d_in[7];
    const float* vm = (const float*)d_in[8];
    const float* gr = (const float*)d_in[9];
    const float* br = (const float*)d_in[10];
    const float* mr = (const float*)d_in[11];
    const float* vr = (const float*)d_in[12];

    float* out = (float*)d_out;

    // workspace layout (floats): pooled [B*C], km [B*72], kr [B*9]
    float* pooled = (float*)d_ws;
    float* km_ws  = pooled + B_ * C_;
    float* kr_ws  = km_ws + B_ * PM_;

    pool_kernel<<<B_ * C_, 256, 0, stream>>>(x, pooled);

    gen_kernel<<<B_, 128, 0, stream>>>(pooled, w_main, w_gate_main, w_rem, w_gate_rem,
                                       gm, bm, mm, vm, gr, br, mr, vr, km_ws, kr_ws);

    dim3 grid(H_ / 2, C_, B_);
    conv_kernel<<<grid, 256, 0, stream>>>(x, km_ws, kr_ws, out);
}

// Round 3
// 237.565 us; speedup vs baseline: 1.0205x; 1.0205x over previous
//
#include <hip/hip_runtime.h>
#include <hip/hip_bf16.h>
#include <math.h>

#define B_ 16
#define C_ 67
#define H_ 128
#define W_ 128
#define MAIN_ 64
#define G_ 8
#define K2_ 9
#define PM_ 72
#define PR_ 9

// ---------------- Kernel 1: global average pool ----------------
// grid: B*C blocks, 256 threads. Each block reduces one (b,c) plane (16384 floats).
__global__ __launch_bounds__(256) void pool_kernel(const float* __restrict__ x,
                                                   float* __restrict__ pooled) {
    int bc = blockIdx.x;
    const float4* p4 = (const float4*)(x + (size_t)bc * (H_ * W_));
    int tid = threadIdx.x;
    float s = 0.f;
    const int n4 = H_ * W_ / 4;  // 4096
    for (int i = tid; i < n4; i += 256) {
        float4 v = p4[i];
        s += (v.x + v.y) + (v.z + v.w);
    }
    // wave64 reduce
    for (int off = 32; off > 0; off >>= 1) s += __shfl_down(s, off, 64);
    __shared__ float red[4];
    if ((tid & 63) == 0) red[tid >> 6] = s;
    __syncthreads();
    if (tid == 0) {
        float t = (red[0] + red[1]) + (red[2] + red[3]);
        pooled[bc] = t * (1.0f / (H_ * W_));
    }
}

// ---------------- Kernel 2: dynamic kernel generation ----------------
// grid: B blocks, 128 threads. Threads 0..71 handle main path, 96..104 handle rem path.
__global__ __launch_bounds__(128) void gen_kernel(
    const float* __restrict__ pooled,
    const float* __restrict__ w_main, const float* __restrict__ w_gate_main,
    const float* __restrict__ w_rem,  const float* __restrict__ w_gate_rem,
    const float* __restrict__ gm, const float* __restrict__ bm,
    const float* __restrict__ mm, const float* __restrict__ vm,
    const float* __restrict__ gr, const float* __restrict__ br,
    const float* __restrict__ mr, const float* __restrict__ vr,
    float* __restrict__ km_out, float* __restrict__ kr_out) {
    int b = blockIdx.x;
    int t = threadIdx.x;
    __shared__ float pl[C_];
    __shared__ float km0[PM_];
    __shared__ float kmb[PM_];
    __shared__ float kr0[PR_];
    __shared__ float krb[PR_];
    if (t < C_) pl[t] = pooled[b * C_ + t];
    __syncthreads();
    if (t < PM_) {
        float s = 0.f;
        for (int c = 0; c < C_; ++c) s += pl[c] * w_main[t * C_ + c];
        km0[t] = s;
    }
    if (t >= 96 && t < 96 + PR_) {
        int p = t - 96;
        float s = 0.f;
        for (int c = 0; c < C_; ++c) s += pl[c] * w_rem[p * C_ + c];
        kr0[p] = s;
    }
    __syncthreads();
    if (t < PM_) {
        float gsum = 0.f;
        for (int q = 0; q < PM_; ++q) gsum += km0[q] * w_gate_main[t * PM_ + q];
        float v = km0[t] * (1.f / (1.f + expf(-gsum)));
        v = gm[t] * (v - mm[t]) * rsqrtf(vm[t] + 1e-5f) + bm[t];
        kmb[t] = v;
    }
    if (t >= 96 && t < 96 + PR_) {
        int p = t - 96;
        float gsum = 0.f;
        for (int q = 0; q < PR_; ++q) gsum += kr0[q] * w_gate_rem[p * PR_ + q];
        float v = kr0[p] * (1.f / (1.f + expf(-gsum)));
        v = gr[p] * (v - mr[p]) * rsqrtf(vr[p] + 1e-5f) + br[p];
        krb[p] = v;
    }
    __syncthreads();
    if (t < PM_) {
        int base = (t / K2_) * K2_;
        float mx = -1e30f;
        for (int k = 0; k < K2_; ++k) mx = fmaxf(mx, kmb[base + k]);
        float den = 0.f;
        for (int k = 0; k < K2_; ++k) den += expf(kmb[base + k] - mx);
        km_out[b * PM_ + t] = expf(kmb[t] - mx) / den;
    }
    if (t >= 96 && t < 96 + PR_) {
        int p = t - 96;
        float mx = -1e30f;
        for (int k = 0; k < K2_; ++k) mx = fmaxf(mx, krb[k]);
        float den = 0.f;
        for (int k = 0; k < K2_; ++k) den += expf(krb[k] - mx);
        kr_out[b * PR_ + p] = expf(krb[p] - mx) / den;
    }
}

// ---------------- Kernel 3: dynamic 3x3 conv (reflect pad) + residual, 4 px/thread ----------------
// grid: (H/8, C, B), 256 threads. Thread t: row = t>>5 (8 rows/block), cols 4*(t&31)..+3.
__global__ __launch_bounds__(256) void conv_kernel(const float* __restrict__ x,
                                                   const float* __restrict__ km,
                                                   const float* __restrict__ kr,
                                                   float* __restrict__ out) {
    const int b = blockIdx.z;
    const int c = blockIdx.y;
    const int t = threadIdx.x;
    const int row_in = t >> 5;      // 0..7
    const int t4 = t & 31;          // col group
    const int h = blockIdx.x * 8 + row_in;
    const int c0 = t4 * 4;

    const float* wp = (c < MAIN_) ? (km + ((size_t)b * G_ + (c >> 3)) * K2_)
                                  : (kr + (size_t)b * K2_);
    float k0 = wp[0], k1 = wp[1], k2 = wp[2],
          k3 = wp[3], k4 = wp[4], k5 = wp[5],
          k6 = wp[6], k7 = wp[7], k8 = wp[8];

    const float* xb = x + ((size_t)b * C_ + c) * (H_ * W_);
    const int hm = (h == 0) ? 1 : h - 1;
    const int hp = (h == H_ - 1) ? H_ - 2 : h + 1;
    const int cl = (c0 == 0) ? 1 : c0 - 1;          // reflect left
    const int cr = (c0 == W_ - 4) ? W_ - 2 : c0 + 4; // reflect right

    const float* r0 = xb + hm * W_;
    const float* r1 = xb + (size_t)h * W_;
    const float* r2 = xb + hp * W_;

    float4 v0 = *(const float4*)(r0 + c0);
    float a0 = r0[cl], f0 = r0[cr];
    float4 v1 = *(const float4*)(r1 + c0);
    float a1 = r1[cl], f1 = r1[cr];
    float4 v2 = *(const float4*)(r2 + c0);
    float a2 = r2[cl], f2 = r2[cr];

    float4 acc;
    acc.x = k0*a0   + k1*v0.x + k2*v0.y
          + k3*a1   + k4*v1.x + k5*v1.y
          + k6*a2   + k7*v2.x + k8*v2.y;
    acc.y = k0*v0.x + k1*v0.y + k2*v0.z
          + k3*v1.x + k4*v1.y + k5*v1.z
          + k6*v2.x + k7*v2.y + k8*v2.z;
    acc.z = k0*v0.y + k1*v0.z + k2*v0.w
          + k3*v1.y + k4*v1.z + k5*v1.w
          + k6*v2.y + k7*v2.z + k8*v2.w;
    acc.w = k0*v0.z + k1*v0.w + k2*f0
          + k3*v1.z + k4*v1.w + k5*f1
          + k6*v2.z + k7*v2.w + k8*f2;

    size_t base = (((size_t)b * C_ + c) * H_ + h) * W_ + c0;
    *(float4*)(out + base) = acc;
    float4 hi;
    hi.x = v1.x - acc.x;
    hi.y = v1.y - acc.y;
    hi.z = v1.z - acc.z;
    hi.w = v1.w - acc.w;
    *(float4*)(out + base + (size_t)B_ * C_ * H_ * W_) = hi;
}

extern "C" void kernel_launch(void* const* d_in, const int* in_sizes, int n_in,
                              void* d_out, int out_size, void* d_ws, size_t ws_size,
                              hipStream_t stream) {
    const float* x           = (const float*)d_in[0];
    const float* w_main      = (const float*)d_in[1];
    const float* w_gate_main = (const float*)d_in[2];
    const float* w_rem       = (const float*)d_in[3];
    const float* w_gate_rem  = (const float*)d_in[4];
    const float* gm = (const float*)d_in[5];
    const float* bm = (const float*)d_in[6];
    const float* mm = (const float*)d_in[7];
    const float* vm = (const float*)d_in[8];
    const float* gr = (const float*)d_in[9];
    const float* br = (const float*)d_in[10];
    const float* mr = (const float*)d_in[11];
    const float* vr = (const float*)d_in[12];

    float* out = (float*)d_out;

    // workspace layout (floats): pooled [B*C], km [B*72], kr [B*9]
    float* pooled = (float*)d_ws;
    float* km_ws  = pooled + B_ * C_;
    float* kr_ws  = km_ws + B_ * PM_;

    pool_kernel<<<B_ * C_, 256, 0, stream>>>(x, pooled);

    gen_kernel<<<B_, 128, 0, stream>>>(pooled, w_main, w_gate_main, w_rem, w_gate_rem,
                                       gm, bm, mm, vm, gr, br, mr, vr, km_ws, kr_ws);

    dim3 grid(H_ / 8, C_, B_);
    conv_kernel<<<grid, 256, 0, stream>>>(x, km_ws, kr_ws, out);
}